// Round 16
// baseline (11462.312 us; speedup 1.0000x reference)
//
#include <hip/hip_runtime.h>

// Two-layer tanh RNN, persistent kernel, MFMA bf16, SELF-VALIDATING TAGGED RINGS.
// Round-16: r11/r15 proved detect-mechanics don't move the 7.5us hop -> the
// serial MALL-RT chain (detect RT + data RT + producer drain RT) is the cost.
// Fix: fuse detect+data into ONE roundtrip. Ring element = u32 (bf16<<16)|tag,
// tag = s+1. Producer: single 4B sc0sc1 store per output - NO drain, NO data
// flag. Consumer: issue 32 loads, validate tags in-register (OR of w^tag,
// low16==0, __all across wave), retry if stale. Torn 16B loads spanning 4
// independent 4B producer stores are caught per-u32. Slot reuse distance =
// DEPTH=4 steps -> tags distinct; WAR gating (below) bounds drift.
//
// Epoch flags (u16) remain ONLY for WAR back-pressure; meaning = "step-s reads
// done" (stored by tid0 AFTER the post-MFMA barrier, fire-and-forget):
//   L0@s before writing h1 slot s&3 (destroys h1[s-4]):
//       gL0 >= s-2 (L0 read h1[s-4] at step s-3), gL1 >= s-3 (L1 read at s-4)
//   L1@s before writing h2 slot (destroys h2[s-4]): gL1 >= s-2
// tid0 polls at step top (pre-compute); the single per-step barrier orders it
// before any tagged store.
//
// Partition = r12 (proven): 256 WGs x 512 thr, wg = layer*128 + rg4*32 + nb32
// (rg4: 16-row group, nb32: 32-feat block). Wave: fb, srcw, kh. Weights
// VGPR-resident 16 short8. L1's two ring matmuls run concurrently on
// different waves, each self-validating (no lane0 waits at all on data).
// One barrier/step: LDS reduce parity-double-buffered (red[2][8][16][17]).

#define SEQ 512
#define BATCH 64
#define HID 1024
#define BH (BATCH * HID)
#define DEPTH 4

typedef __attribute__((ext_vector_type(8))) short short8;
typedef __attribute__((ext_vector_type(4))) float f32x4;
typedef __attribute__((ext_vector_type(4))) unsigned int u32x4;

__device__ __forceinline__ unsigned short f32_to_bf16_rne(float f) {
    unsigned int u = __float_as_uint(f);
    u += 0x7FFFu + ((u >> 16) & 1u);
    return (unsigned short)(u >> 16);
}

__device__ __forceinline__ short8 cvt8(float4 f0, float4 f1) {
    short8 w;
    w[0] = (short)f32_to_bf16_rne(f0.x);
    w[1] = (short)f32_to_bf16_rne(f0.y);
    w[2] = (short)f32_to_bf16_rne(f0.z);
    w[3] = (short)f32_to_bf16_rne(f0.w);
    w[4] = (short)f32_to_bf16_rne(f1.x);
    w[5] = (short)f32_to_bf16_rne(f1.y);
    w[6] = (short)f32_to_bf16_rne(f1.z);
    w[7] = (short)f32_to_bf16_rne(f1.w);
    return w;
}

__device__ __forceinline__ void vm_wait0() {
    asm volatile("s_waitcnt vmcnt(0)" ::: "memory");
    __builtin_amdgcn_sched_barrier(0);   // rule 18
}

// device-coherent stores (MALL)
__device__ __forceinline__ void st_cc32(unsigned* p, unsigned v) {
    asm volatile("global_store_dword %0, %1, off sc0 sc1"
                 :: "v"(p), "v"(v) : "memory");
}
__device__ __forceinline__ void st_cc16(unsigned short* p, unsigned v) {
    asm volatile("global_store_short %0, %1, off sc0 sc1"
                 :: "v"(p), "v"(v) : "memory");
}

__device__ __forceinline__ unsigned min_u16x4(u32x4 w, unsigned mn) {
    #pragma unroll
    for (int j = 0; j < 4; ++j) {
        unsigned lo = w[j] & 0xFFFFu, hi = w[j] >> 16;
        mn = mn < lo ? mn : lo;
        mn = mn < hi ? mn : hi;
    }
    return mn;
}

// WAR wait: min over 32 u16 slots (64B = 4 dwordx4), off critical path
__device__ __forceinline__ void wait_grp32(const unsigned short* f, int target) {
    if (target <= 0) return;
    for (;;) {
        u32x4 r[4];
        #pragma unroll
        for (int i = 0; i < 4; ++i)
            asm volatile("global_load_dwordx4 %0, %1, off sc0 sc1"
                         : "=v"(r[i]) : "v"((const unsigned int*)f + i * 4) : "memory");
        asm volatile("s_waitcnt vmcnt(0)" ::: "memory");
        __builtin_amdgcn_sched_barrier(0);
        unsigned mn = 0xFFFFu;
        #pragma unroll
        for (int i = 0; i < 4; ++i) mn = min_u16x4(r[i], mn);
        if ((int)mn >= target) return;
        __builtin_amdgcn_s_sleep(1);
    }
}

#define MFMA16(W, A, ACC) \
    ACC = __builtin_amdgcn_mfma_f32_16x16x32_bf16((W), (A), (ACC), 0, 0, 0)

// Self-validating ring matmul attempt: 32 coherent loads (1 MALL roundtrip),
// tag-validate all 128 u32s, then extract bf16 and run 16 MFMA.
// Returns false (acc untouched) if any element stale/torn.
__device__ __forceinline__ bool try_ring_mm(const unsigned* pr, unsigned tag,
                                            const short8* wreg, f32x4& accio) {
    u32x4 lo[16], hi[16];
    #pragma unroll
    for (int ks = 0; ks < 16; ++ks) {
        const unsigned* p = pr + ks * 32;
        asm volatile("global_load_dwordx4 %0, %1, off sc0 sc1"
                     : "=v"(lo[ks]) : "v"(p) : "memory");
        asm volatile("global_load_dwordx4 %0, %1, off sc0 sc1"
                     : "=v"(hi[ks]) : "v"(p + 4) : "memory");
    }
    vm_wait0();
    unsigned d = 0;
    #pragma unroll
    for (int ks = 0; ks < 16; ++ks) {
        #pragma unroll
        for (int j = 0; j < 4; ++j) {
            d |= lo[ks][j] ^ tag;
            d |= hi[ks][j] ^ tag;
        }
    }
    if (!__all((d & 0xFFFFu) == 0u)) return false;
    f32x4 acc = accio;
    #pragma unroll
    for (int ks = 0; ks < 16; ++ks) {
        u32x4 pk;
        pk[0] = (lo[ks][0] >> 16) | (lo[ks][1] & 0xFFFF0000u);
        pk[1] = (lo[ks][2] >> 16) | (lo[ks][3] & 0xFFFF0000u);
        pk[2] = (hi[ks][0] >> 16) | (hi[ks][1] & 0xFFFF0000u);
        pk[3] = (hi[ks][2] >> 16) | (hi[ks][3] & 0xFFFF0000u);
        short8 a = __builtin_bit_cast(short8, pk);
        MFMA16(wreg[ks], a, acc);
    }
    accio = acc;
    return true;
}

__device__ __forceinline__ void ring_mm_poll(const unsigned* pr, unsigned tag,
                                             const short8* wreg, f32x4& acc) {
    while (!try_ring_mm(pr, tag, wreg, acc))
        __builtin_amdgcn_s_sleep(1);
}

__global__ void cvt_f32_bf16(const float* __restrict__ src,
                             unsigned short* __restrict__ dst, int n4) {
    int i = blockIdx.x * blockDim.x + threadIdx.x;
    int stride = gridDim.x * blockDim.x;
    for (; i < n4; i += stride) {
        float4 f = ((const float4*)src)[i];
        ushort4 o;
        o.x = f32_to_bf16_rne(f.x);
        o.y = f32_to_bf16_rne(f.y);
        o.z = f32_to_bf16_rne(f.z);
        o.w = f32_to_bf16_rne(f.w);
        ((ushort4*)dst)[i] = o;
    }
}

__global__ void init_ws(uint4* __restrict__ p, int n16) {
    int i = blockIdx.x * blockDim.x + threadIdx.x;
    if (i < n16) p[i] = make_uint4(0u, 0u, 0u, 0u);
}

__global__ __launch_bounds__(512, 1) void rnn_mfma(
    const float* __restrict__ x,
    const unsigned short* __restrict__ xb, int use_xb,
    const float* __restrict__ Wi0, const float* __restrict__ bi0,
    const float* __restrict__ Wh0, const float* __restrict__ bh0,
    const float* __restrict__ Wi1, const float* __restrict__ bi1,
    const float* __restrict__ Wh1, const float* __restrict__ bh1,
    float* __restrict__ out,
    unsigned* __restrict__ rings32,
    unsigned short* __restrict__ flags)
{
    unsigned* h1r = rings32;                 // [4][64][1024] u32 tagged
    unsigned* h2r = rings32 + DEPTH * BH;

    const int tid   = threadIdx.x;
    const int wg    = blockIdx.x;        // 0..255
    const int layer = wg >> 7;
    const int rg4   = (wg >> 5) & 3;     // 16-row group
    const int nb32  = wg & 31;           // 32-feat block
    const int wv    = tid >> 6;          // 0..7
    const int lane  = tid & 63;
    const int fb    = wv >> 2;
    const int srcw  = (wv >> 1) & 1;
    const int kh    = wv & 1;

    unsigned short* gL0 = flags + (0 * 4 + rg4) * 64;
    unsigned short* gL1 = flags + (1 * 4 + rg4) * 64;
    unsigned short* ep_self = (layer ? gL1 : gL0) + nb32;

    // ---- resident weights: 16 short8 = 64 VGPRs ----
    const float* Wsel = layer ? (srcw ? Wh1 : Wi1) : (srcw ? Wh0 : Wi0);
    const int f_w = nb32 * 32 + fb * 16 + (lane & 15);
    const int kcb = kh * 512 + (lane >> 4) * 8;
    short8 wreg[16];
    {
        const float* rw = Wsel + (size_t)f_w * HID + kcb;
        #pragma unroll
        for (int ks = 0; ks < 16; ++ks)
            wreg[ks] = cvt8(*(const float4*)(rw + ks * 32),
                            *(const float4*)(rw + ks * 32 + 4));
    }

    const int arow = rg4 * 16 + (lane & 15);
    const size_t aoff = (size_t)arow * HID + kcb;   // element offset

    // reduce constants: thread -> (feat 0..31, row 0..15), 1 output each
    const int r_feat = tid & 31;
    const int r_row  = tid >> 5;
    const int gf     = nb32 * 32 + r_feat;
    const int grow   = rg4 * 16 + r_row;
    const float* biv = layer ? bi1 : bi0;
    const float* bhv = layer ? bh1 : bh0;
    const float biasv = biv[gf] + bhv[gf];
    const int rw_base = (r_feat >> 4) * 4;

    __shared__ float red[2][8][16][17];   // parity double-buffer, 17.4 KB

    for (int s = 0; s < SEQ; ++s) {
        const int par = s & 1;
        f32x4 acc = {0.f, 0.f, 0.f, 0.f};

        // ---- WAR back-pressure (tid0, pre-compute; barrier orders it) ----
        if (tid == 0) {
            if (layer == 0) {
                wait_grp32(gL0, s - (DEPTH - 2));   // own group read h1[s-4]
                wait_grp32(gL1, s - (DEPTH - 1));   // L1 read h1[s-4]
            } else {
                wait_grp32(gL1, s - (DEPTH - 2));   // L1 read h2[s-4]
            }
        }

        if (layer == 0 && srcw == 0) {
            // ---- x_s @ Wi0^T : static input, plain loads ----
            if (use_xb) {
                const unsigned short* px = xb + (size_t)s * BH + aoff;
                #pragma unroll
                for (int ks = 0; ks < 16; ++ks) {
                    short8 a = *(const short8*)(px + ks * 32);
                    MFMA16(wreg[ks], a, acc);
                }
            } else {
                const float* px = x + (size_t)s * BH + aoff;
                #pragma unroll
                for (int ks = 0; ks < 16; ++ks) {
                    short8 a = cvt8(*(const float4*)(px + ks * 32),
                                    *(const float4*)(px + ks * 32 + 4));
                    MFMA16(wreg[ks], a, acc);
                }
            }
        } else if (layer == 0) {
            // ---- h1[s-1] @ Wh0^T : tag = s ----
            ring_mm_poll(h1r + (size_t)((s - 1) & (DEPTH - 1)) * BH + aoff,
                         (unsigned)s, wreg, acc);
        } else if (srcw == 1) {
            // ---- h2[s-1] @ Wh1^T : tag = s ----
            ring_mm_poll(h2r + (size_t)((s - 1) & (DEPTH - 1)) * BH + aoff,
                         (unsigned)s, wreg, acc);
        } else {
            // ---- h1[s] @ Wi1^T : tag = s+1 (critical cross-layer) ----
            ring_mm_poll(h1r + (size_t)(s & (DEPTH - 1)) * BH + aoff,
                         (unsigned)(s + 1), wreg, acc);
        }

        // ---- partials to LDS (parity buffer) ----
        #pragma unroll
        for (int r = 0; r < 4; ++r)
            red[par][wv][4 * (lane >> 4) + r][lane & 15] = acc[r];
        __syncthreads();   // ONLY barrier per step

        // reads of step s are complete for the whole WG -> WAR signal
        if (tid == 0)
            st_cc16(ep_self, (unsigned)(s + 1));

        // ---- reduce + tanh + tagged ring store (fire-and-forget) ----
        {
            const int ff = r_feat & 15;
            float v = red[par][rw_base][ff][r_row] + red[par][rw_base + 1][ff][r_row]
                    + red[par][rw_base + 2][ff][r_row] + red[par][rw_base + 3][ff][r_row]
                    + biasv;
            v = tanhf(v);
            unsigned tagged = ((unsigned)f32_to_bf16_rne(v) << 16) | (unsigned)(s + 1);
            unsigned* ring_self = (layer ? h2r : h1r) + (size_t)(s & (DEPTH - 1)) * BH;
            st_cc32(ring_self + (size_t)grow * HID + gf, tagged);

            // f32 outputs (plain cached stores, off critical path)
            if (layer == 1) {
                out[(size_t)s * BH + (size_t)grow * HID + gf] = v;
                if (s == SEQ - 1)
                    out[(size_t)SEQ * BH + BH + (size_t)grow * HID + gf] = v; // h_final[1]
            } else if (s == SEQ - 1) {
                out[(size_t)SEQ * BH + (size_t)grow * HID + gf] = v;          // h_final[0]
            }
        }
        // no trailing barrier: next step writes red[par^1]; waves can't drift
        // 2 steps (each step's barrier bounds drift to 1).
    }
}

extern "C" void kernel_launch(void* const* d_in, const int* in_sizes, int n_in,
                              void* d_out, int out_size, void* d_ws, size_t ws_size,
                              hipStream_t stream) {
    const float* xp   = (const float*)d_in[0];
    const float* Wi0p = (const float*)d_in[1];
    const float* bi0p = (const float*)d_in[2];
    const float* Wh0p = (const float*)d_in[3];
    const float* bh0p = (const float*)d_in[4];
    const float* Wi1p = (const float*)d_in[5];
    const float* bi1p = (const float*)d_in[6];
    const float* Wh1p = (const float*)d_in[7];
    const float* bh1p = (const float*)d_in[8];
    float* outp = (float*)d_out;

    // ws layout: tagged rings 2 MiB | flags (4 KiB pad) | xb 64 MiB
    unsigned* rings32 = (unsigned*)d_ws;
    const size_t ring_bytes = (size_t)2 * DEPTH * BH * sizeof(unsigned);   // 2 MiB
    unsigned short* flags = (unsigned short*)((char*)d_ws + ring_bytes);
    const size_t flag_pad = 4096;
    unsigned short* xb = (unsigned short*)((char*)d_ws + ring_bytes + flag_pad);
    const size_t xb_bytes = (size_t)SEQ * BH * 2;                          // 64 MiB
    const int use_xb = (ws_size >= ring_bytes + flag_pad + xb_bytes) ? 1 : 0;

    {
        const int n16 = (int)((ring_bytes + flag_pad) / 16);
        init_ws<<<(n16 + 255) / 256, 256, 0, stream>>>((uint4*)d_ws, n16);
    }
    if (use_xb)
        cvt_f32_bf16<<<2048, 256, 0, stream>>>(xp, xb, SEQ * BH / 4);

    rnn_mfma<<<dim3(256), dim3(512), 0, stream>>>(
        xp, xb, use_xb,
        Wi0p, bi0p, Wh0p, bh0p, Wi1p, bi1p, Wh1p, bh1p,
        outp, rings32, flags);
}

// Round 18
// 10344.289 us; speedup vs baseline: 1.1081x; 1.1081x over previous
//
#include <hip/hip_runtime.h>

// Two-layer tanh RNN, persistent kernel, MFMA bf16, epoch sync, NO BARRIERS.
// Round-18 = round-17 with the handshake race fixed: summed cnt[fb] replaced
// by PER-FEEDER sequence counters post[fb][3]. r17's race: feeders have
// unequal waits, so feeder progress skews; sum==3(s+1) can be reached while
// one feeder is a full step behind (its stale same-parity partial summed).
// Per-feeder counters are skew-proof: finisher requires each >= s+1.
//
// Structure (r12 partition, proven): 256 WGs x 512 thr, wg = layer*128 +
// rg4*32 + nb32 (rg4: 16-row group, nb32: 32-feat block). Wave wv: fb=wv>>2,
// r2=wv&3 (0,1 feeders; 2 sibling; 3 finisher), kh=r2&1.
//   L0: r2<2 = x@Wi0 K-halves (no wait); r2>=2 = h1[s-1]@Wh0 (critical).
//   L1: r2<2 = h2[s-1]@Wh1 (wait gL1>=s); r2>=2 = h1[s]@Wi1 (wait gL0>=s+1).
// Weights 16 short8 = 64 VGPRs. Ring matmul = 16 coherent loads in ONE batch
// + 16 MFMA. Rings u16 bf16, DEPTH=8. Flags: u16, (layer,rg4) group = 64
// slots (32 WGs x 2 fb) = 128B scan.
// WAR: L0 finisher fuses gL1 >= s-(DEPTH-1); h2-ring WAR transitive via the
// early waves' gL1>=s wait (their post => all L1 WGs completed s-1 => old
// h2 slot reads long done).
// done_[fb] back-pressures feeders to LDS parity. Rule-18 everywhere.

#define SEQ 512
#define BATCH 64
#define HID 1024
#define BH (BATCH * HID)
#define DEPTH 8

typedef __attribute__((ext_vector_type(8))) short short8;
typedef __attribute__((ext_vector_type(4))) float f32x4;
typedef __attribute__((ext_vector_type(4))) unsigned int u32x4;

__device__ __forceinline__ unsigned short f32_to_bf16_rne(float f) {
    unsigned int u = __float_as_uint(f);
    u += 0x7FFFu + ((u >> 16) & 1u);
    return (unsigned short)(u >> 16);
}

__device__ __forceinline__ short8 cvt8(float4 f0, float4 f1) {
    short8 w;
    w[0] = (short)f32_to_bf16_rne(f0.x);
    w[1] = (short)f32_to_bf16_rne(f0.y);
    w[2] = (short)f32_to_bf16_rne(f0.z);
    w[3] = (short)f32_to_bf16_rne(f0.w);
    w[4] = (short)f32_to_bf16_rne(f1.x);
    w[5] = (short)f32_to_bf16_rne(f1.y);
    w[6] = (short)f32_to_bf16_rne(f1.z);
    w[7] = (short)f32_to_bf16_rne(f1.w);
    return w;
}

// 16B device-coherent load (MALL), pipelineable; caller waits.
__device__ __forceinline__ void ld_cc16(short8& d, const unsigned short* p) {
    asm volatile("global_load_dwordx4 %0, %1, off sc0 sc1"
                 : "=v"(d) : "v"(p) : "memory");
}

__device__ __forceinline__ void vm_wait0() {
    asm volatile("s_waitcnt vmcnt(0)" ::: "memory");
    __builtin_amdgcn_sched_barrier(0);   // rule 18
}

__device__ __forceinline__ void st_cc16(unsigned short* p, unsigned v) {
    asm volatile("global_store_short %0, %1, off sc0 sc1"
                 :: "v"(p), "v"(v) : "memory");
}
__device__ __forceinline__ void st_cc64(unsigned short* p, unsigned long long v) {
    asm volatile("global_store_dwordx2 %0, %1, off sc0 sc1"
                 :: "v"(p), "v"(v) : "memory");
}

__device__ __forceinline__ unsigned long long pack4_bf16(float a, float b, float c, float d) {
    return (unsigned long long)f32_to_bf16_rne(a)
         | ((unsigned long long)f32_to_bf16_rne(b) << 16)
         | ((unsigned long long)f32_to_bf16_rne(c) << 32)
         | ((unsigned long long)f32_to_bf16_rne(d) << 48);
}

__device__ __forceinline__ unsigned min_u16x4(u32x4 w, unsigned mn) {
    #pragma unroll
    for (int j = 0; j < 4; ++j) {
        unsigned lo = w[j] & 0xFFFFu, hi = w[j] >> 16;
        mn = mn < lo ? mn : lo;
        mn = mn < hi ? mn : hi;
    }
    return mn;
}

// wait on one 64-slot group (128B = 8 dwordx4), one roundtrip per poll
__device__ __forceinline__ void wait_one64(const unsigned short* f, int target) {
    if (target <= 0) return;
    for (;;) {
        u32x4 r[8];
        #pragma unroll
        for (int i = 0; i < 8; ++i)
            asm volatile("global_load_dwordx4 %0, %1, off sc0 sc1"
                         : "=v"(r[i]) : "v"((const unsigned int*)f + i * 4) : "memory");
        asm volatile("s_waitcnt vmcnt(0)" ::: "memory");
        __builtin_amdgcn_sched_barrier(0);
        unsigned mn = 0xFFFFu;
        #pragma unroll
        for (int i = 0; i < 8; ++i) mn = min_u16x4(r[i], mn);
        if ((int)mn >= target) return;
        __builtin_amdgcn_s_sleep(1);
    }
}

// fused dual-group wait: both 128B scans in one batch
__device__ __forceinline__ void wait_two64(const unsigned short* f0, int t0,
                                           const unsigned short* f1, int t1) {
    if (t0 <= 0 && t1 <= 0) return;
    for (;;) {
        u32x4 r0[8], r1[8];
        #pragma unroll
        for (int i = 0; i < 8; ++i)
            asm volatile("global_load_dwordx4 %0, %1, off sc0 sc1"
                         : "=v"(r0[i]) : "v"((const unsigned int*)f0 + i * 4) : "memory");
        #pragma unroll
        for (int i = 0; i < 8; ++i)
            asm volatile("global_load_dwordx4 %0, %1, off sc0 sc1"
                         : "=v"(r1[i]) : "v"((const unsigned int*)f1 + i * 4) : "memory");
        asm volatile("s_waitcnt vmcnt(0)" ::: "memory");
        __builtin_amdgcn_sched_barrier(0);
        unsigned m0 = 0xFFFFu, m1 = 0xFFFFu;
        #pragma unroll
        for (int i = 0; i < 8; ++i) { m0 = min_u16x4(r0[i], m0); m1 = min_u16x4(r1[i], m1); }
        if ((int)m0 >= t0 && (int)m1 >= t1) return;
        __builtin_amdgcn_s_sleep(1);
    }
}

#define MFMA16(W, A, ACC) \
    ACC = __builtin_amdgcn_mfma_f32_16x16x32_bf16((W), (A), (ACC), 0, 0, 0)

// 16-ks ring matmul, ONE load batch (single MALL roundtrip) + 16 MFMA.
__device__ __forceinline__ void ring_mm16(const unsigned short* pr, size_t aoff,
                                          const short8* wreg, f32x4& acc) {
    short8 a[16];
    #pragma unroll
    for (int k = 0; k < 16; ++k)
        ld_cc16(a[k], pr + aoff + k * 32);
    vm_wait0();
    #pragma unroll
    for (int k = 0; k < 16; ++k)
        MFMA16(wreg[k], a[k], acc);
}

__global__ void cvt_f32_bf16(const float* __restrict__ src,
                             unsigned short* __restrict__ dst, int n4) {
    int i = blockIdx.x * blockDim.x + threadIdx.x;
    int stride = gridDim.x * blockDim.x;
    for (; i < n4; i += stride) {
        float4 f = ((const float4*)src)[i];
        ushort4 o;
        o.x = f32_to_bf16_rne(f.x);
        o.y = f32_to_bf16_rne(f.y);
        o.z = f32_to_bf16_rne(f.z);
        o.w = f32_to_bf16_rne(f.w);
        ((ushort4*)dst)[i] = o;
    }
}

__global__ void init_ws(uint4* __restrict__ p, int n16) {
    int i = blockIdx.x * blockDim.x + threadIdx.x;
    if (i < n16) p[i] = make_uint4(0u, 0u, 0u, 0u);
}

__global__ __launch_bounds__(512, 1) void rnn_mfma(
    const float* __restrict__ x,
    const unsigned short* __restrict__ xb, int use_xb,
    const float* __restrict__ Wi0, const float* __restrict__ bi0,
    const float* __restrict__ Wh0, const float* __restrict__ bh0,
    const float* __restrict__ Wi1, const float* __restrict__ bi1,
    const float* __restrict__ Wh1, const float* __restrict__ bh1,
    float* __restrict__ out,
    unsigned short* __restrict__ rings,
    unsigned short* __restrict__ flags)
{
    unsigned short* h1ring = rings;                  // [8][64][1024] bf16
    unsigned short* h2ring = rings + DEPTH * BH;

    const int tid   = threadIdx.x;
    const int wg    = blockIdx.x;        // 0..255
    const int layer = wg >> 7;
    const int rg4   = (wg >> 5) & 3;     // 16-row group
    const int nb32  = wg & 31;           // 32-feat block
    const int wv    = tid >> 6;          // 0..7
    const int lane  = tid & 63;
    const int fb    = wv >> 2;           // 16-feat half of the 32-feat block
    const int r2    = wv & 3;            // 0,1 feeders; 2 sibling; 3 finisher
    const int kh    = r2 & 1;            // K half

    unsigned short* gL0 = flags + (0 * 4 + rg4) * 64;   // 64 u16 = 128B
    unsigned short* gL1 = flags + (1 * 4 + rg4) * 64;
    unsigned short* ep_self = (layer ? gL1 : gL0) + nb32 * 2 + fb;

    // ---- resident weights: 16 short8 = 64 VGPRs ----
    const float* Wsel = layer ? (r2 < 2 ? Wh1 : Wi1) : (r2 < 2 ? Wi0 : Wh0);
    const int f_w = nb32 * 32 + fb * 16 + (lane & 15);
    const int kcb = kh * 512 + (lane >> 4) * 8;
    short8 wreg[16];
    {
        const float* rw = Wsel + (size_t)f_w * HID + kcb;
        #pragma unroll
        for (int ks = 0; ks < 16; ++ks)
            wreg[ks] = cvt8(*(const float4*)(rw + ks * 32),
                            *(const float4*)(rw + ks * 32 + 4));
    }

    // activation (B-operand) address: one 16-row tile
    const int arow = rg4 * 16 + (lane & 15);
    const size_t aoff = (size_t)arow * HID + kcb;

    // finisher output mapping: lane -> (4 consecutive feats, 1 row)
    const int f0   = nb32 * 32 + fb * 16 + 4 * (lane >> 4);
    const int grow = rg4 * 16 + (lane & 15);
    const float* biv = layer ? bi1 : bi0;
    const float* bhv = layer ? bh1 : bh0;
    float bias4[4];
    #pragma unroll
    for (int r = 0; r < 4; ++r) bias4[r] = biv[f0 + r] + bhv[f0 + r];

    __shared__ float part[2][2][3][16][17];   // [par][fb][slot][feat][row] 13KB
    __shared__ unsigned post[2][3];           // per-feeder step counters
    __shared__ unsigned done_[2];             // steps consumed by finisher

    if (tid == 0) {
        post[0][0] = post[0][1] = post[0][2] = 0u;
        post[1][0] = post[1][1] = post[1][2] = 0u;
        done_[0] = done_[1] = 0u;
    }
    __syncthreads();   // one-time init barrier only

    for (int s = 0; s < SEQ; ++s) {
        const int par = s & 1;
        f32x4 acc = {0.f, 0.f, 0.f, 0.f};

        if (layer == 0 && r2 < 2) {
            // ---- x_s @ Wi0^T : static input, plain loads, no wait ----
            if (use_xb) {
                const unsigned short* px = xb + (size_t)s * BH + aoff;
                #pragma unroll
                for (int ks = 0; ks < 16; ++ks) {
                    short8 a = *(const short8*)(px + ks * 32);
                    MFMA16(wreg[ks], a, acc);
                }
            } else {
                const float* px = x + (size_t)s * BH + aoff;
                #pragma unroll
                for (int ks = 0; ks < 16; ++ks) {
                    short8 a = cvt8(*(const float4*)(px + ks * 32),
                                    *(const float4*)(px + ks * 32 + 4));
                    MFMA16(wreg[ks], a, acc);
                }
            }
        } else if (layer == 0) {
            // ---- h1[s-1] @ Wh0^T (critical) ----
            if (r2 == 3) wait_two64(gL0, s, gL1, s - (DEPTH - 1));  // data + WAR
            else         wait_one64(gL0, s);
            ring_mm16(h1ring + (size_t)((s - 1) & (DEPTH - 1)) * BH, aoff, wreg, acc);
        } else if (r2 < 2) {
            // ---- h2[s-1] @ Wh1^T (early) ----
            wait_one64(gL1, s);
            ring_mm16(h2ring + (size_t)((s - 1) & (DEPTH - 1)) * BH, aoff, wreg, acc);
        } else {
            // ---- h1[s] @ Wi1^T (critical cross-layer) ----
            wait_one64(gL0, s + 1);
            ring_mm16(h1ring + (size_t)(s & (DEPTH - 1)) * BH, aoff, wreg, acc);
        }

        if (r2 != 3) {
            // ---- feeder: wait LDS parity free, post partial ----
            while ((int)__hip_atomic_load(&done_[fb], __ATOMIC_ACQUIRE,
                                          __HIP_MEMORY_SCOPE_WORKGROUP) < s - 1)
                __builtin_amdgcn_s_sleep(0);
            #pragma unroll
            for (int r = 0; r < 4; ++r)
                part[par][fb][r2][4 * (lane >> 4) + r][lane & 15] = acc[r];
            if (lane == 0)
                __hip_atomic_store(&post[fb][r2], (unsigned)(s + 1),
                                   __ATOMIC_RELEASE, __HIP_MEMORY_SCOPE_WORKGROUP);
        } else {
            // ---- finisher: wait ALL THREE feeders at step s (skew-proof) ----
            const unsigned need = (unsigned)(s + 1);
            for (;;) {
                unsigned p0 = __hip_atomic_load(&post[fb][0], __ATOMIC_ACQUIRE,
                                                __HIP_MEMORY_SCOPE_WORKGROUP);
                unsigned p1 = __hip_atomic_load(&post[fb][1], __ATOMIC_ACQUIRE,
                                                __HIP_MEMORY_SCOPE_WORKGROUP);
                unsigned p2 = __hip_atomic_load(&post[fb][2], __ATOMIC_ACQUIRE,
                                                __HIP_MEMORY_SCOPE_WORKGROUP);
                if (p0 >= need && p1 >= need && p2 >= need) break;
                __builtin_amdgcn_s_sleep(0);
            }
            #pragma unroll
            for (int r = 0; r < 4; ++r) {
                const int ff = 4 * (lane >> 4) + r;
                acc[r] += part[par][fb][0][ff][lane & 15]
                        + part[par][fb][1][ff][lane & 15]
                        + part[par][fb][2][ff][lane & 15] + bias4[r];
            }
            if (lane == 0)
                __hip_atomic_store(&done_[fb], (unsigned)(s + 1), __ATOMIC_RELEASE,
                                   __HIP_MEMORY_SCOPE_WORKGROUP);
            float v0 = tanhf(acc[0]), v1 = tanhf(acc[1]);
            float v2 = tanhf(acc[2]), v3 = tanhf(acc[3]);
            unsigned short* ring_self =
                (layer ? h2ring : h1ring) + (size_t)(s & (DEPTH - 1)) * BH;
            st_cc64(ring_self + (size_t)grow * HID + f0, pack4_bf16(v0, v1, v2, v3));
            vm_wait0();                             // drain own wave's 8B stores
            if (lane == 0)
                st_cc16(ep_self, (unsigned)(s + 1));
            // f32 outputs (off critical path, after signal)
            if (layer == 1) {
                *(float4*)(out + (size_t)s * BH + (size_t)grow * HID + f0) =
                    make_float4(v0, v1, v2, v3);
                if (s == SEQ - 1)
                    *(float4*)(out + (size_t)SEQ * BH + BH + (size_t)grow * HID + f0) =
                        make_float4(v0, v1, v2, v3);            // h_final[1]
            } else if (s == SEQ - 1) {
                *(float4*)(out + (size_t)SEQ * BH + (size_t)grow * HID + f0) =
                    make_float4(v0, v1, v2, v3);                // h_final[0]
            }
        }
    }
}

extern "C" void kernel_launch(void* const* d_in, const int* in_sizes, int n_in,
                              void* d_out, int out_size, void* d_ws, size_t ws_size,
                              hipStream_t stream) {
    const float* xp   = (const float*)d_in[0];
    const float* Wi0p = (const float*)d_in[1];
    const float* bi0p = (const float*)d_in[2];
    const float* Wh0p = (const float*)d_in[3];
    const float* bh0p = (const float*)d_in[4];
    const float* Wi1p = (const float*)d_in[5];
    const float* bi1p = (const float*)d_in[6];
    const float* Wh1p = (const float*)d_in[7];
    const float* bh1p = (const float*)d_in[8];
    float* outp = (float*)d_out;

    // ws layout: rings 2 MiB | flags 1 KiB (pad 4 KiB) | xb 64 MiB
    unsigned short* rings = (unsigned short*)d_ws;
    const size_t ring_bytes = (size_t)2 * DEPTH * BH * sizeof(unsigned short); // 2 MiB
    unsigned short* flags = (unsigned short*)((char*)d_ws + ring_bytes);
    const size_t flag_pad = 4096;
    unsigned short* xb = (unsigned short*)((char*)d_ws + ring_bytes + flag_pad);
    const size_t xb_bytes = (size_t)SEQ * BH * 2;                              // 64 MiB
    const int use_xb = (ws_size >= ring_bytes + flag_pad + xb_bytes) ? 1 : 0;

    {
        const int n16 = (int)((ring_bytes + flag_pad) / 16);
        init_ws<<<(n16 + 255) / 256, 256, 0, stream>>>((uint4*)d_ws, n16);
    }
    if (use_xb)
        cvt_f32_bf16<<<2048, 256, 0, stream>>>(xp, xb, SEQ * BH / 4);

    rnn_mfma<<<dim3(256), dim3(512), 0, stream>>>(
        xp, xb, use_xb,
        Wi0p, bi0p, Wh0p, bh0p, Wi1p, bi1p, Wh1p, bh1p,
        outp, rings, flags);
}

// Round 19
// 8179.721 us; speedup vs baseline: 1.4013x; 1.2646x over previous
//
#include <hip/hip_runtime.h>

// Two-layer tanh RNN, persistent kernel, MFMA bf16, epoch sync + TAGGED RINGS.
// Round-19 = r12 skeleton (proven 3.86ms: partition, 2 barriers/step, lane0
// epoch waits, one-batch ring loads) + ONE change: ring element = u32
// (bf16<<16)|tag, tag=s+1. Producer: tagged store -> barrier -> flag, with NO
// vmcnt(0) store-drain (the drain moves into the consumer's next vm_wait0,
// where it overlaps detect latency). Consumer: epoch wait as r12 (so data is
// almost always landed -> retries rare; r16's mistake was using validation AS
// the detect), then per-8ks-chunk tag-validate BEFORE MFMA, retry chunk on
// rare failure. r18 lesson: barriers are cheap, wave choreography is not.
//
// 256 WGs x 512 thr: wg = layer*128 + rg4*32 + nb32 (rg4: 16-row group,
// nb32: 32-feat block). Wave wv: fb=wv>>2, srcw=(wv>>1)&1, kh=wv&1.
// Weights 16 short8 = 64 VGPRs. Rings u32 tagged, DEPTH=4 (2 MiB).
// Flags: u16 epochs, (layer,rg4) group = 32 slots = 64B scan.
//   L0 srcw1@s: gL0>=s && gL1>=s-3 (fused; h1 slot WAR vs L1 lag)
//   L1 srcw1@s: gL1>=s.   L1 srcw0@s: gL0>=s+1.
// WAR airtight => no stale-tag livelock: overwrite of slot (tag t) is gated
// on all readers' flags; readers flag only after validated reads.

#define SEQ 512
#define BATCH 64
#define HID 1024
#define BH (BATCH * HID)
#define DEPTH 4

typedef __attribute__((ext_vector_type(8))) short short8;
typedef __attribute__((ext_vector_type(4))) float f32x4;
typedef __attribute__((ext_vector_type(4))) unsigned int u32x4;

__device__ __forceinline__ unsigned short f32_to_bf16_rne(float f) {
    unsigned int u = __float_as_uint(f);
    u += 0x7FFFu + ((u >> 16) & 1u);
    return (unsigned short)(u >> 16);
}

__device__ __forceinline__ short8 cvt8(float4 f0, float4 f1) {
    short8 w;
    w[0] = (short)f32_to_bf16_rne(f0.x);
    w[1] = (short)f32_to_bf16_rne(f0.y);
    w[2] = (short)f32_to_bf16_rne(f0.z);
    w[3] = (short)f32_to_bf16_rne(f0.w);
    w[4] = (short)f32_to_bf16_rne(f1.x);
    w[5] = (short)f32_to_bf16_rne(f1.y);
    w[6] = (short)f32_to_bf16_rne(f1.z);
    w[7] = (short)f32_to_bf16_rne(f1.w);
    return w;
}

__device__ __forceinline__ void vm_wait0() {
    asm volatile("s_waitcnt vmcnt(0)" ::: "memory");
    __builtin_amdgcn_sched_barrier(0);   // rule 18
}

__device__ __forceinline__ void st_cc32(unsigned* p, unsigned v) {
    asm volatile("global_store_dword %0, %1, off sc0 sc1"
                 :: "v"(p), "v"(v) : "memory");
}
__device__ __forceinline__ void st_cc16(unsigned short* p, unsigned v) {
    asm volatile("global_store_short %0, %1, off sc0 sc1"
                 :: "v"(p), "v"(v) : "memory");
}

__device__ __forceinline__ unsigned min_u16x4(u32x4 w, unsigned mn) {
    #pragma unroll
    for (int j = 0; j < 4; ++j) {
        unsigned lo = w[j] & 0xFFFFu, hi = w[j] >> 16;
        mn = mn < lo ? mn : lo;
        mn = mn < hi ? mn : hi;
    }
    return mn;
}

// wait on one group: 32 u16 slots = 64B = 4 dwordx4, one roundtrip per poll
__device__ __forceinline__ void wait_one32(const unsigned short* f, int target) {
    if (target <= 0) return;
    for (;;) {
        u32x4 r[4];
        #pragma unroll
        for (int i = 0; i < 4; ++i)
            asm volatile("global_load_dwordx4 %0, %1, off sc0 sc1"
                         : "=v"(r[i]) : "v"((const unsigned int*)f + i * 4) : "memory");
        asm volatile("s_waitcnt vmcnt(0)" ::: "memory");
        __builtin_amdgcn_sched_barrier(0);
        unsigned mn = 0xFFFFu;
        #pragma unroll
        for (int i = 0; i < 4; ++i) mn = min_u16x4(r[i], mn);
        if ((int)mn >= target) return;
        __builtin_amdgcn_s_sleep(1);
    }
}

// fused dual-group wait: both 64B scans in one batch, one roundtrip
__device__ __forceinline__ void wait_two32(const unsigned short* f0, int t0,
                                           const unsigned short* f1, int t1) {
    if (t0 <= 0 && t1 <= 0) return;
    for (;;) {
        u32x4 r0[4], r1[4];
        #pragma unroll
        for (int i = 0; i < 4; ++i)
            asm volatile("global_load_dwordx4 %0, %1, off sc0 sc1"
                         : "=v"(r0[i]) : "v"((const unsigned int*)f0 + i * 4) : "memory");
        #pragma unroll
        for (int i = 0; i < 4; ++i)
            asm volatile("global_load_dwordx4 %0, %1, off sc0 sc1"
                         : "=v"(r1[i]) : "v"((const unsigned int*)f1 + i * 4) : "memory");
        asm volatile("s_waitcnt vmcnt(0)" ::: "memory");
        __builtin_amdgcn_sched_barrier(0);
        unsigned m0 = 0xFFFFu, m1 = 0xFFFFu;
        #pragma unroll
        for (int i = 0; i < 4; ++i) { m0 = min_u16x4(r0[i], m0); m1 = min_u16x4(r1[i], m1); }
        if ((int)m0 >= t0 && (int)m1 >= t1) return;
        __builtin_amdgcn_s_sleep(1);
    }
}

#define MFMA16(W, A, ACC) \
    ACC = __builtin_amdgcn_mfma_f32_16x16x32_bf16((W), (A), (ACC), 0, 0, 0)

// Tagged ring matmul: 2 chunks x 8 ks. Per chunk: 16 dwordx4 loads (one MALL
// roundtrip), validate 64 u32 tags in-register, retry chunk if any stale
// (rare: epoch flag already confirmed production), then unpack + 8 MFMA.
__device__ __forceinline__ void ring_mm_tag(const unsigned* base, unsigned tag,
                                            const short8* wreg, f32x4& acc) {
    #pragma unroll
    for (int c = 0; c < 2; ++c) {
        u32x4 lo[8], hi[8];
        for (;;) {
            #pragma unroll
            for (int k = 0; k < 8; ++k) {
                const unsigned* p = base + (c * 8 + k) * 32;
                asm volatile("global_load_dwordx4 %0, %1, off sc0 sc1"
                             : "=v"(lo[k]) : "v"(p) : "memory");
                asm volatile("global_load_dwordx4 %0, %1, off sc0 sc1"
                             : "=v"(hi[k]) : "v"(p + 4) : "memory");
            }
            asm volatile("s_waitcnt vmcnt(0)" ::: "memory");
            __builtin_amdgcn_sched_barrier(0);
            unsigned d = 0;
            #pragma unroll
            for (int k = 0; k < 8; ++k) {
                #pragma unroll
                for (int j = 0; j < 4; ++j) { d |= lo[k][j] ^ tag; d |= hi[k][j] ^ tag; }
            }
            if (__all((d & 0xFFFFu) == 0u)) break;
            __builtin_amdgcn_s_sleep(1);
        }
        #pragma unroll
        for (int k = 0; k < 8; ++k) {
            u32x4 pk;
            pk[0] = (lo[k][0] >> 16) | (lo[k][1] & 0xFFFF0000u);
            pk[1] = (lo[k][2] >> 16) | (lo[k][3] & 0xFFFF0000u);
            pk[2] = (hi[k][0] >> 16) | (hi[k][1] & 0xFFFF0000u);
            pk[3] = (hi[k][2] >> 16) | (hi[k][3] & 0xFFFF0000u);
            short8 a = __builtin_bit_cast(short8, pk);
            MFMA16(wreg[c * 8 + k], a, acc);
        }
    }
}

__global__ void cvt_f32_bf16(const float* __restrict__ src,
                             unsigned short* __restrict__ dst, int n4) {
    int i = blockIdx.x * blockDim.x + threadIdx.x;
    int stride = gridDim.x * blockDim.x;
    for (; i < n4; i += stride) {
        float4 f = ((const float4*)src)[i];
        ushort4 o;
        o.x = f32_to_bf16_rne(f.x);
        o.y = f32_to_bf16_rne(f.y);
        o.z = f32_to_bf16_rne(f.z);
        o.w = f32_to_bf16_rne(f.w);
        ((ushort4*)dst)[i] = o;
    }
}

__global__ void init_ws(uint4* __restrict__ p, int n16) {
    int i = blockIdx.x * blockDim.x + threadIdx.x;
    if (i < n16) p[i] = make_uint4(0u, 0u, 0u, 0u);
}

__global__ __launch_bounds__(512, 1) void rnn_mfma(
    const float* __restrict__ x,
    const unsigned short* __restrict__ xb, int use_xb,
    const float* __restrict__ Wi0, const float* __restrict__ bi0,
    const float* __restrict__ Wh0, const float* __restrict__ bh0,
    const float* __restrict__ Wi1, const float* __restrict__ bi1,
    const float* __restrict__ Wh1, const float* __restrict__ bh1,
    float* __restrict__ out,
    unsigned* __restrict__ rings32,
    unsigned short* __restrict__ flags)
{
    unsigned* h1r = rings32;                 // [4][64][1024] u32 tagged
    unsigned* h2r = rings32 + DEPTH * BH;

    const int tid   = threadIdx.x;
    const int wg    = blockIdx.x;        // 0..255
    const int layer = wg >> 7;
    const int rg4   = (wg >> 5) & 3;     // 16-row group
    const int nb32  = wg & 31;           // 32-feat block
    const int wv    = tid >> 6;          // 0..7
    const int lane  = tid & 63;
    const int fb    = wv >> 2;           // 16-feat half (0/1)
    const int srcw  = (wv >> 1) & 1;     // 0: first source, 1: recurrent
    const int kh    = wv & 1;            // K half

    unsigned short* gL0 = flags + (0 * 4 + rg4) * 64;
    unsigned short* gL1 = flags + (1 * 4 + rg4) * 64;
    unsigned short* ep_self = (layer ? gL1 : gL0) + nb32;

    // ---- resident weights: 16 short8 = 64 VGPRs ----
    const float* Wsel = layer ? (srcw ? Wh1 : Wi1) : (srcw ? Wh0 : Wi0);
    const int f_w = nb32 * 32 + fb * 16 + (lane & 15);
    const int kcb = kh * 512 + (lane >> 4) * 8;
    short8 wreg[16];
    {
        const float* rw = Wsel + (size_t)f_w * HID + kcb;
        #pragma unroll
        for (int ks = 0; ks < 16; ++ks)
            wreg[ks] = cvt8(*(const float4*)(rw + ks * 32),
                            *(const float4*)(rw + ks * 32 + 4));
    }

    // activation address: one 16-row tile (element offset, u32 ring)
    const int arow = rg4 * 16 + (lane & 15);
    const size_t aoff = (size_t)arow * HID + kcb;

    // reduce constants: thread -> (feat 0..31, row 0..15)
    const int r_feat = tid & 31;
    const int r_row  = tid >> 5;
    const int gf     = nb32 * 32 + r_feat;
    const int grow   = rg4 * 16 + r_row;
    const float* biv = layer ? bi1 : bi0;
    const float* bhv = layer ? bh1 : bh0;
    const float biasv = biv[gf] + bhv[gf];
    const int rw_base = (r_feat >> 4) * 4;

    __shared__ float red[8][16][17];

    for (int s = 0; s < SEQ; ++s) {
        f32x4 acc = {0.f, 0.f, 0.f, 0.f};

        if (layer == 0 && srcw == 0) {
            // ---- x_s @ Wi0^T : static input, plain loads, no wait ----
            if (use_xb) {
                const unsigned short* px = xb + (size_t)s * BH + aoff;
                #pragma unroll
                for (int ks = 0; ks < 16; ++ks) {
                    short8 a = *(const short8*)(px + ks * 32);
                    MFMA16(wreg[ks], a, acc);
                }
            } else {
                const float* px = x + (size_t)s * BH + aoff;
                #pragma unroll
                for (int ks = 0; ks < 16; ++ks) {
                    short8 a = cvt8(*(const float4*)(px + ks * 32),
                                    *(const float4*)(px + ks * 32 + 4));
                    MFMA16(wreg[ks], a, acc);
                }
            }
        } else if (layer == 0) {
            // ---- h1[s-1] @ Wh0^T (critical; + h1-slot WAR vs L1 lag) ----
            if (lane == 0) wait_two32(gL0, s, gL1, s - (DEPTH - 1));
            ring_mm_tag(h1r + (size_t)((s - 1) & (DEPTH - 1)) * BH + aoff,
                        (unsigned)s, wreg, acc);
        } else if (srcw == 1) {
            // ---- h2[s-1] @ Wh1^T ----
            if (lane == 0) wait_one32(gL1, s);
            ring_mm_tag(h2r + (size_t)((s - 1) & (DEPTH - 1)) * BH + aoff,
                        (unsigned)s, wreg, acc);
        } else {
            // ---- h1[s] @ Wi1^T (critical cross-layer) ----
            if (lane == 0) wait_one32(gL0, s + 1);
            ring_mm_tag(h1r + (size_t)(s & (DEPTH - 1)) * BH + aoff,
                        (unsigned)(s + 1), wreg, acc);
        }

        // ---- partials to LDS: red[wave][feat16][row16] ----
        #pragma unroll
        for (int r = 0; r < 4; ++r)
            red[wv][4 * (lane >> 4) + r][lane & 15] = acc[r];
        __syncthreads();

        // ---- reduce (4 partials) + tanh + TAGGED ring store (no drain) ----
        float v;
        {
            const int ff = r_feat & 15;
            v = red[rw_base][ff][r_row] + red[rw_base + 1][ff][r_row]
              + red[rw_base + 2][ff][r_row] + red[rw_base + 3][ff][r_row] + biasv;
            v = tanhf(v);
            unsigned tagged = ((unsigned)f32_to_bf16_rne(v) << 16) | (unsigned)(s + 1);
            unsigned* ring_self = (layer ? h2r : h1r) + (size_t)(s & (DEPTH - 1)) * BH;
            st_cc32(ring_self + (size_t)grow * HID + gf, tagged);
        }

        __syncthreads();                 // order flag after all stores ISSUED
        if (tid == 0)
            st_cc16(ep_self, (unsigned)(s + 1));

        // ---- f32 outputs (off critical path, after signal) ----
        if (layer == 1) {
            out[(size_t)s * BH + (size_t)grow * HID + gf] = v;
            if (s == SEQ - 1)
                out[(size_t)SEQ * BH + BH + (size_t)grow * HID + gf] = v;  // h_final[1]
        } else if (s == SEQ - 1) {
            out[(size_t)SEQ * BH + (size_t)grow * HID + gf] = v;           // h_final[0]
        }
    }
}

extern "C" void kernel_launch(void* const* d_in, const int* in_sizes, int n_in,
                              void* d_out, int out_size, void* d_ws, size_t ws_size,
                              hipStream_t stream) {
    const float* xp   = (const float*)d_in[0];
    const float* Wi0p = (const float*)d_in[1];
    const float* bi0p = (const float*)d_in[2];
    const float* Wh0p = (const float*)d_in[3];
    const float* bh0p = (const float*)d_in[4];
    const float* Wi1p = (const float*)d_in[5];
    const float* bi1p = (const float*)d_in[6];
    const float* Wh1p = (const float*)d_in[7];
    const float* bh1p = (const float*)d_in[8];
    float* outp = (float*)d_out;

    // ws layout: tagged rings 2 MiB | flags 1 KiB (pad 4 KiB) | xb 64 MiB
    unsigned* rings32 = (unsigned*)d_ws;
    const size_t ring_bytes = (size_t)2 * DEPTH * BH * sizeof(unsigned);   // 2 MiB
    unsigned short* flags = (unsigned short*)((char*)d_ws + ring_bytes);
    const size_t flag_pad = 4096;
    unsigned short* xb = (unsigned short*)((char*)d_ws + ring_bytes + flag_pad);
    const size_t xb_bytes = (size_t)SEQ * BH * 2;                          // 64 MiB
    const int use_xb = (ws_size >= ring_bytes + flag_pad + xb_bytes) ? 1 : 0;

    {
        const int n16 = (int)((ring_bytes + flag_pad) / 16);
        init_ws<<<(n16 + 255) / 256, 256, 0, stream>>>((uint4*)d_ws, n16);
    }
    if (use_xb)
        cvt_f32_bf16<<<2048, 256, 0, stream>>>(xp, xb, SEQ * BH / 4);

    rnn_mfma<<<dim3(256), dim3(512), 0, stream>>>(
        xp, xb, use_xb,
        Wi0p, bi0p, Wh0p, bh0p, Wi1p, bi1p, Wh1p, bh1p,
        outp, rings32, flags);
}

// Round 20
// 3849.677 us; speedup vs baseline: 2.9775x; 2.1248x over previous
//
#include <hip/hip_runtime.h>

// Two-layer tanh RNN, persistent kernel (plain launch), MFMA bf16, epoch sync.
// FINAL (= round-12, proven 3.86 ms): batch-diagonal row-groups + fat WGs.
//   256 WGs x 512 thr (8 waves): wg = layer*128 + rg4*32 + nb32.
//   rg4: 4 independent row-groups of 16 batch rows; nb32: 32-feat block.
//   Sync domain = 32 WGs; detect = one 64B u16 scan.
//   Wave wv: fb=wv>>2 (16-feat half), srcw=(wv>>1)&1, kh=wv&1.
//   Weights VGPR-resident 16 x short8 = 64 VGPRs; ONE 16-row tile per wave ->
//   ring matmul = 16 coherent loads in ONE batch (1 MALL roundtrip) + 16 MFMA.
//   L1's h2-part (srcw1) and h1[s]-part (srcw0) run CONCURRENTLY on different
//   waves, each with its own lane0 wait (wave-divergence sync).
// Ring: 8-deep; WAR: L0 srcw1 also waits epL1 >= s-7.
//   L0 srcw1@s: epL0>=s && epL1>=s-7 (fused scan). L1 srcw1@s: epL1>=s.
//   L1 srcw0@s: epL0>=s+1.
// Producer: LDS reduce -> tanh -> u16 ring stores (sc0 sc1) -> vmcnt(0) ->
// barrier -> tid0 epoch store. Rule-18 sched_barrier after every asm wait.
//
// Structural floor (measured over rounds 11-19): per-step hop = detect RT
// (~2us) + data RT (~2us) + store-drain+flag visibility (~2.5us) + compute
// (~1us) ~= 7.5us; x512 steps = 3.84ms ~= measured. Alternatives tested and
// closed: poll mechanics (r11/r15 neutral), XCD-local L2 fabric (r13/r14
// hang), tag-fused detect+data (r16/r19 re-fetch storm), barrier-free
// choreography (r17/r18 spin overhead).

#define SEQ 512
#define BATCH 64
#define HID 1024
#define BH (BATCH * HID)
#define DEPTH 8

typedef __attribute__((ext_vector_type(8))) short short8;
typedef __attribute__((ext_vector_type(4))) float f32x4;
typedef __attribute__((ext_vector_type(4))) unsigned int u32x4;

__device__ __forceinline__ unsigned short f32_to_bf16_rne(float f) {
    unsigned int u = __float_as_uint(f);
    u += 0x7FFFu + ((u >> 16) & 1u);
    return (unsigned short)(u >> 16);
}

__device__ __forceinline__ short8 cvt8(float4 f0, float4 f1) {
    short8 w;
    w[0] = (short)f32_to_bf16_rne(f0.x);
    w[1] = (short)f32_to_bf16_rne(f0.y);
    w[2] = (short)f32_to_bf16_rne(f0.z);
    w[3] = (short)f32_to_bf16_rne(f0.w);
    w[4] = (short)f32_to_bf16_rne(f1.x);
    w[5] = (short)f32_to_bf16_rne(f1.y);
    w[6] = (short)f32_to_bf16_rne(f1.z);
    w[7] = (short)f32_to_bf16_rne(f1.w);
    return w;
}

// 16B device-coherent load (served at MALL), pipelineable; caller waits.
__device__ __forceinline__ void ld_cc16(short8& d, const unsigned short* p) {
    asm volatile("global_load_dwordx4 %0, %1, off sc0 sc1"
                 : "=v"(d) : "v"(p) : "memory");
}

__device__ __forceinline__ void vm_wait0() {
    asm volatile("s_waitcnt vmcnt(0)" ::: "memory");
    __builtin_amdgcn_sched_barrier(0);   // rule 18
}

// u16 device-coherent store (epochs, ring values)
__device__ __forceinline__ void st_cc16(unsigned short* p, unsigned v) {
    asm volatile("global_store_short %0, %1, off sc0 sc1"
                 :: "v"(p), "v"(v) : "memory");
}

__device__ __forceinline__ unsigned min_u16x4(u32x4 w, unsigned mn) {
    #pragma unroll
    for (int j = 0; j < 4; ++j) {
        unsigned lo = w[j] & 0xFFFFu, hi = w[j] >> 16;
        mn = mn < lo ? mn : lo;
        mn = mn < hi ? mn : hi;
    }
    return mn;
}

// wait on one group: 32 u16 slots = 64B = 4 dwordx4, one roundtrip per poll
__device__ __forceinline__ void wait_one32(const unsigned short* f, int target) {
    if (target <= 0) return;
    for (;;) {
        u32x4 r[4];
        #pragma unroll
        for (int i = 0; i < 4; ++i)
            asm volatile("global_load_dwordx4 %0, %1, off sc0 sc1"
                         : "=v"(r[i]) : "v"((const unsigned int*)f + i * 4) : "memory");
        asm volatile("s_waitcnt vmcnt(0)" ::: "memory");
        __builtin_amdgcn_sched_barrier(0);
        unsigned mn = 0xFFFFu;
        #pragma unroll
        for (int i = 0; i < 4; ++i) mn = min_u16x4(r[i], mn);
        if ((int)mn >= target) return;
        __builtin_amdgcn_s_sleep(1);
    }
}

// fused dual-group wait: both 64B scans in one batch, one roundtrip
__device__ __forceinline__ void wait_two32(const unsigned short* f0, int t0,
                                           const unsigned short* f1, int t1) {
    if (t0 <= 0 && t1 <= 0) return;
    for (;;) {
        u32x4 r0[4], r1[4];
        #pragma unroll
        for (int i = 0; i < 4; ++i)
            asm volatile("global_load_dwordx4 %0, %1, off sc0 sc1"
                         : "=v"(r0[i]) : "v"((const unsigned int*)f0 + i * 4) : "memory");
        #pragma unroll
        for (int i = 0; i < 4; ++i)
            asm volatile("global_load_dwordx4 %0, %1, off sc0 sc1"
                         : "=v"(r1[i]) : "v"((const unsigned int*)f1 + i * 4) : "memory");
        asm volatile("s_waitcnt vmcnt(0)" ::: "memory");
        __builtin_amdgcn_sched_barrier(0);
        unsigned m0 = 0xFFFFu, m1 = 0xFFFFu;
        #pragma unroll
        for (int i = 0; i < 4; ++i) { m0 = min_u16x4(r0[i], m0); m1 = min_u16x4(r1[i], m1); }
        if ((int)m0 >= t0 && (int)m1 >= t1) return;
        __builtin_amdgcn_s_sleep(1);
    }
}

#define MFMA16(W, A, ACC) \
    ACC = __builtin_amdgcn_mfma_f32_16x16x32_bf16((W), (A), (ACC), 0, 0, 0)

// 16-ks ring matmul, ONE load batch (single MALL roundtrip) + 16 MFMA.
__device__ __forceinline__ void ring_mm16(const unsigned short* pr, size_t aoff,
                                          const short8* wreg, f32x4& acc) {
    short8 a[16];
    #pragma unroll
    for (int k = 0; k < 16; ++k)
        ld_cc16(a[k], pr + aoff + k * 32);
    vm_wait0();
    #pragma unroll
    for (int k = 0; k < 16; ++k)
        MFMA16(wreg[k], a[k], acc);
}

__global__ void cvt_f32_bf16(const float* __restrict__ src,
                             unsigned short* __restrict__ dst, int n4) {
    int i = blockIdx.x * blockDim.x + threadIdx.x;
    int stride = gridDim.x * blockDim.x;
    for (; i < n4; i += stride) {
        float4 f = ((const float4*)src)[i];
        ushort4 o;
        o.x = f32_to_bf16_rne(f.x);
        o.y = f32_to_bf16_rne(f.y);
        o.z = f32_to_bf16_rne(f.z);
        o.w = f32_to_bf16_rne(f.w);
        ((ushort4*)dst)[i] = o;
    }
}

__global__ void init_ws(uint4* __restrict__ p, int n16) {
    int i = blockIdx.x * blockDim.x + threadIdx.x;
    if (i < n16) p[i] = make_uint4(0u, 0u, 0u, 0u);
}

__global__ __launch_bounds__(512, 1) void rnn_mfma(
    const float* __restrict__ x,
    const unsigned short* __restrict__ xb, int use_xb,
    const float* __restrict__ Wi0, const float* __restrict__ bi0,
    const float* __restrict__ Wh0, const float* __restrict__ bh0,
    const float* __restrict__ Wi1, const float* __restrict__ bi1,
    const float* __restrict__ Wh1, const float* __restrict__ bh1,
    float* __restrict__ out,
    unsigned short* __restrict__ rings,
    unsigned short* __restrict__ flags)
{
    unsigned short* h1ring = rings;                  // [8][64][1024] bf16
    unsigned short* h2ring = rings + DEPTH * BH;     // [8][64][1024] bf16

    const int tid   = threadIdx.x;
    const int wg    = blockIdx.x;        // 0..255
    const int layer = wg >> 7;           // 0/1
    const int rg4   = (wg >> 5) & 3;     // row-group: 16 batch rows
    const int nb32  = wg & 31;           // 32-feat block
    const int wv    = tid >> 6;          // 0..7
    const int lane  = tid & 63;
    const int fb    = wv >> 2;           // 16-feat half (0/1)
    const int srcw  = (wv >> 1) & 1;     // 0: first source, 1: recurrent
    const int kh    = wv & 1;            // K half

    unsigned short* gL0 = flags + (0 * 4 + rg4) * 64;   // 128B-strided groups
    unsigned short* gL1 = flags + (1 * 4 + rg4) * 64;
    unsigned short* ep_self = (layer ? gL1 : gL0) + nb32;

    // ---- resident weights: 16 short8 = 64 VGPRs ----
    const float* Wsel = layer ? (srcw ? Wh1 : Wi1) : (srcw ? Wh0 : Wi0);
    const int f_w = nb32 * 32 + fb * 16 + (lane & 15);
    const int kcb = kh * 512 + (lane >> 4) * 8;
    short8 wreg[16];
    {
        const float* rw = Wsel + (size_t)f_w * HID + kcb;
        #pragma unroll
        for (int ks = 0; ks < 16; ++ks)
            wreg[ks] = cvt8(*(const float4*)(rw + ks * 32),
                            *(const float4*)(rw + ks * 32 + 4));
    }

    // activation (B-operand) address: one 16-row tile
    const int arow = rg4 * 16 + (lane & 15);
    const size_t aoff = (size_t)arow * HID + kcb;

    // reduce-phase constants: thread -> (feat 0..31, row 0..15)
    const int r_feat = tid & 31;
    const int r_row  = tid >> 5;
    const int gf     = nb32 * 32 + r_feat;          // global feature
    const int grow   = rg4 * 16 + r_row;            // global batch row
    const float* biv = layer ? bi1 : bi0;
    const float* bhv = layer ? bh1 : bh0;
    const float biasv = biv[gf] + bhv[gf];
    const int rw_base = (r_feat >> 4) * 4;          // partial waves fb*4..+3

    __shared__ float red[8][16][17];                // 8.7 KB

    for (int s = 0; s < SEQ; ++s) {
        f32x4 acc = {0.f, 0.f, 0.f, 0.f};

        if (layer == 0 && srcw == 0) {
            // ---- x_s @ Wi0^T : static input, plain loads, no wait ----
            if (use_xb) {
                const unsigned short* px = xb + (size_t)s * BH + aoff;
                #pragma unroll
                for (int ks = 0; ks < 16; ++ks) {
                    short8 a = *(const short8*)(px + ks * 32);
                    MFMA16(wreg[ks], a, acc);
                }
            } else {
                const float* px = x + (size_t)s * BH + aoff;
                #pragma unroll
                for (int ks = 0; ks < 16; ++ks) {
                    short8 a = cvt8(*(const float4*)(px + ks * 32),
                                    *(const float4*)(px + ks * 32 + 4));
                    MFMA16(wreg[ks], a, acc);
                }
            }
        } else if (layer == 0) {
            // ---- h1[s-1] @ Wh0^T (critical; + ring WAR check) ----
            if (lane == 0) wait_two32(gL0, s, gL1, s - (DEPTH - 1));
            ring_mm16(h1ring + (size_t)((s - 1) & (DEPTH - 1)) * BH, aoff, wreg, acc);
        } else if (srcw == 1) {
            // ---- h2[s-1] @ Wh1^T (own-group recurrent) ----
            if (lane == 0) wait_one32(gL1, s);
            ring_mm16(h2ring + (size_t)((s - 1) & (DEPTH - 1)) * BH, aoff, wreg, acc);
        } else {
            // ---- h1[s] @ Wi1^T (critical cross-layer) ----
            if (lane == 0) wait_one32(gL0, s + 1);
            ring_mm16(h1ring + (size_t)(s & (DEPTH - 1)) * BH, aoff, wreg, acc);
        }

        // ---- partials to LDS: red[wave][feat16][row16] ----
        #pragma unroll
        for (int r = 0; r < 4; ++r)
            red[wv][4 * (lane >> 4) + r][lane & 15] = acc[r];
        __syncthreads();

        // ---- reduce (4 partials) + tanh + u16 ring store: all 512 thr ----
        float v;
        {
            const int ff = r_feat & 15;
            v = red[rw_base][ff][r_row] + red[rw_base + 1][ff][r_row]
              + red[rw_base + 2][ff][r_row] + red[rw_base + 3][ff][r_row] + biasv;
            v = tanhf(v);
            unsigned short* ring_self =
                (layer ? h2ring : h1ring) + (size_t)(s & (DEPTH - 1)) * BH;
            st_cc16(ring_self + (size_t)grow * HID + gf, f32_to_bf16_rne(v));
        }

        asm volatile("s_waitcnt vmcnt(0)" ::: "memory");   // ring stores at MALL
        __builtin_amdgcn_sched_barrier(0);
        __syncthreads();                                   // all waves acked
        if (tid == 0)
            st_cc16(ep_self, (unsigned)(s + 1));

        // ---- f32 outputs (off critical path, after signal) ----
        if (layer == 1) {
            out[(size_t)s * BH + (size_t)grow * HID + gf] = v;
            if (s == SEQ - 1)
                out[(size_t)SEQ * BH + BH + (size_t)grow * HID + gf] = v;  // h_final[1]
        } else if (s == SEQ - 1) {
            out[(size_t)SEQ * BH + (size_t)grow * HID + gf] = v;           // h_final[0]
        }
    }
}

extern "C" void kernel_launch(void* const* d_in, const int* in_sizes, int n_in,
                              void* d_out, int out_size, void* d_ws, size_t ws_size,
                              hipStream_t stream) {
    const float* xp   = (const float*)d_in[0];
    const float* Wi0p = (const float*)d_in[1];
    const float* bi0p = (const float*)d_in[2];
    const float* Wh0p = (const float*)d_in[3];
    const float* bh0p = (const float*)d_in[4];
    const float* Wi1p = (const float*)d_in[5];
    const float* bi1p = (const float*)d_in[6];
    const float* Wh1p = (const float*)d_in[7];
    const float* bh1p = (const float*)d_in[8];
    float* outp = (float*)d_out;

    // ws layout: rings 2 MiB | flags 1 KiB (pad 4 KiB) | xb 64 MiB
    unsigned short* rings = (unsigned short*)d_ws;
    const size_t ring_bytes = (size_t)2 * DEPTH * BH * sizeof(unsigned short); // 2 MiB
    unsigned short* flags = (unsigned short*)((char*)d_ws + ring_bytes);
    const size_t flag_pad = 4096;
    unsigned short* xb = (unsigned short*)((char*)d_ws + ring_bytes + flag_pad);
    const size_t xb_bytes = (size_t)SEQ * BH * 2;                              // 64 MiB
    const int use_xb = (ws_size >= ring_bytes + flag_pad + xb_bytes) ? 1 : 0;

    {
        const int n16 = (int)((ring_bytes + flag_pad) / 16);
        init_ws<<<(n16 + 255) / 256, 256, 0, stream>>>((uint4*)d_ws, n16);
    }
    if (use_xb)
        cvt_f32_bf16<<<2048, 256, 0, stream>>>(xp, xb, SEQ * BH / 4);

    rnn_mfma<<<dim3(256), dim3(512), 0, stream>>>(
        xp, xb, use_xb,
        Wi0p, bi0p, Wh0p, bh0p, Wi1p, bi1p, Wh1p, bh1p,
        outp, rings, flags);
}